// Round 1
// baseline (1455.175 us; speedup 1.0000x reference)
//
#include <hip/hip_runtime.h>

#define NN 50000
#define NE 800000
#define D 128

// ---------------------------------------------------------------------------
// Kernel 1: scatter  agg[row[e]] += ew[e] * x[col[e]]
// 32 threads per edge, each handles one float4 (4 of the 128 features).
// ---------------------------------------------------------------------------
__global__ __launch_bounds__(256) void scatter_kernel(
    const float* __restrict__ x,
    const float* __restrict__ ew,
    const int* __restrict__ erow,
    const int* __restrict__ ecol,
    float* __restrict__ agg)
{
    int tid = blockIdx.x * 256 + threadIdx.x;
    int e = tid >> 5;
    int q = tid & 31;
    if (e >= NE) return;
    float w = ew[e];
    int r = erow[e];
    int c = ecol[e];
    const float4* x4 = (const float4*)x;
    float4 v = x4[(size_t)c * 32 + q];
    float* dst = agg + (size_t)r * D + q * 4;
    atomicAdd(dst + 0, w * v.x);
    atomicAdd(dst + 1, w * v.y);
    atomicAdd(dst + 2, w * v.z);
    atomicAdd(dst + 3, w * v.w);
}

// ---------------------------------------------------------------------------
// Kernel 2: out = agg @ W + bias   (fp32 vector GEMM, LDS-tiled)
// Block: 256 threads, 64 output rows x 128 cols; per-thread 8 rows x 4 cols.
// K tiled in halves of 64. LDS: W-tile 32KB + transposed x-tile ~17.4KB.
// xT stride 68 floats: keeps float4 (16B) alignment, spreads banks.
// ---------------------------------------------------------------------------
#define BR 64
#define KT 64
#define XS (BR + 4)   // 68: 68*4B = 272B, multiple of 16 -> b128-aligned rows

__global__ __launch_bounds__(256) void gemm_bias_kernel(
    const float* __restrict__ agg,
    const float* __restrict__ W,
    const float* __restrict__ bias,
    float* __restrict__ out)
{
    __shared__ float Wt[KT * D];    // Wt[k][c]
    __shared__ float xT[KT * XS];   // xT[k][r]

    int t = threadIdx.x;
    int row0 = blockIdx.x * BR;
    int tx = t & 31;        // column group
    int ty = t >> 5;        // row group
    int c0 = tx * 4;
    int r0 = ty * 8;

    float acc[8][4] = {};

    for (int kt = 0; kt < D; kt += KT) {
        // ---- stage W tile (KT x D = 8192 floats = 2048 float4) ----
        {
            const float4* Wg = (const float4*)(W + (size_t)kt * D);
            float4* Ws = (float4*)Wt;
            #pragma unroll
            for (int i = 0; i < 8; ++i)
                Ws[t + i * 256] = Wg[t + i * 256];
        }
        // ---- stage x tile transposed (BR rows x KT cols = 1024 float4) ----
        #pragma unroll
        for (int i = 0; i < 4; ++i) {
            int v = t + i * 256;
            int r = v >> 4;      // [0,64) row within tile
            int q = v & 15;      // float4 index within the KT=64 floats
            int grow = row0 + r;
            float4 g = make_float4(0.f, 0.f, 0.f, 0.f);
            if (grow < NN)
                g = *(const float4*)(agg + (size_t)grow * D + kt + q * 4);
            xT[(q * 4 + 0) * XS + r] = g.x;
            xT[(q * 4 + 1) * XS + r] = g.y;
            xT[(q * 4 + 2) * XS + r] = g.z;
            xT[(q * 4 + 3) * XS + r] = g.w;
        }
        __syncthreads();

        // ---- MAC loop ----
        #pragma unroll 4
        for (int k = 0; k < KT; ++k) {
            float4 wv = *(const float4*)(Wt + k * D + c0);
            float4 xa = *(const float4*)(xT + k * XS + r0);
            float4 xb = *(const float4*)(xT + k * XS + r0 + 4);
            float xs[8] = {xa.x, xa.y, xa.z, xa.w, xb.x, xb.y, xb.z, xb.w};
            float ws[4] = {wv.x, wv.y, wv.z, wv.w};
            #pragma unroll
            for (int i = 0; i < 8; ++i)
                #pragma unroll
                for (int j = 0; j < 4; ++j)
                    acc[i][j] += xs[i] * ws[j];
        }
        __syncthreads();
    }

    // ---- epilogue: add bias, store ----
    float4 bv = *(const float4*)(bias + c0);
    #pragma unroll
    for (int i = 0; i < 8; ++i) {
        int grow = row0 + r0 + i;
        if (grow < NN) {
            float4 o;
            o.x = acc[i][0] + bv.x;
            o.y = acc[i][1] + bv.y;
            o.z = acc[i][2] + bv.z;
            o.w = acc[i][3] + bv.w;
            *(float4*)(out + (size_t)grow * D + c0) = o;
        }
    }
}

extern "C" void kernel_launch(void* const* d_in, const int* in_sizes, int n_in,
                              void* d_out, int out_size, void* d_ws, size_t ws_size,
                              hipStream_t stream) {
    const float* x    = (const float*)d_in[0];   // [NN, D]
    const float* W    = (const float*)d_in[1];   // [D, D]
    const float* bias = (const float*)d_in[2];   // [D]
    const float* ew   = (const float*)d_in[3];   // [NE]
    const int*   erow = (const int*)d_in[4];     // [NE]
    const int*   ecol = (const int*)d_in[5];     // [NE]
    float* out = (float*)d_out;                  // [NN, D]
    float* agg = (float*)d_ws;                   // [NN, D] scratch

    // zero the aggregation buffer (ws is poisoned 0xAA before every launch)
    hipMemsetAsync(agg, 0, (size_t)NN * D * sizeof(float), stream);

    // scatter: agg[row] += w * x[col]
    {
        long long total = (long long)NE * 32;
        int grid = (int)((total + 255) / 256);
        scatter_kernel<<<grid, 256, 0, stream>>>(x, ew, erow, ecol, agg);
    }

    // out = agg @ W + bias
    {
        int grid = (NN + BR - 1) / BR;
        gemm_bias_kernel<<<grid, 256, 0, stream>>>(agg, W, bias, out);
    }
}

// Round 2
// 376.946 us; speedup vs baseline: 3.8604x; 3.8604x over previous
//
#include <hip/hip_runtime.h>

#define NN 50000
#define NE 800000
#define D 128

// ws layout (floats/ints), 16B-aligned strides
#define AGG_OFF   0                         // 50000*128 floats = 25.6 MB
#define CNT_OFF   (NN * D)                  // counts: 50016 ints
#define NPAD      50016
#define START_OFF (CNT_OFF + NPAD)          // start: 50001 (+pad) ints
#define CUR_OFF   (START_OFF + NPAD)        // cursor: 50016 ints
#define CSR_OFF   (CUR_OFF + NPAD)          // csr: 800000 int2 = 6.4 MB

// ---------------------------------------------------------------------------
// 1) histogram of edge rows
// ---------------------------------------------------------------------------
__global__ __launch_bounds__(256) void hist_kernel(
    const int* __restrict__ erow, int* __restrict__ counts)
{
    int e = blockIdx.x * 256 + threadIdx.x;
    if (e < NE) atomicAdd(&counts[erow[e]], 1);
}

// ---------------------------------------------------------------------------
// 2) single-block exclusive scan of counts -> start[] and cursor[]
// ---------------------------------------------------------------------------
#define SCAN_T 1024
__global__ __launch_bounds__(SCAN_T) void scan_kernel(
    const int* __restrict__ counts, int* __restrict__ start, int* __restrict__ cursor)
{
    __shared__ int sums[SCAN_T];
    int t = threadIdx.x;
    const int CH = (NN + SCAN_T - 1) / SCAN_T;  // 49
    int base = t * CH;
    int s = 0;
    for (int i = 0; i < CH; ++i) {
        int idx = base + i;
        if (idx < NN) s += counts[idx];
    }
    sums[t] = s;
    __syncthreads();
    for (int off = 1; off < SCAN_T; off <<= 1) {
        int v = (t >= off) ? sums[t - off] : 0;
        __syncthreads();
        sums[t] += v;
        __syncthreads();
    }
    int run = (t == 0) ? 0 : sums[t - 1];
    for (int i = 0; i < CH; ++i) {
        int idx = base + i;
        if (idx < NN) {
            start[idx] = run;
            cursor[idx] = run;
            run += counts[idx];
        }
    }
    if (t == SCAN_T - 1) start[NN] = run;  // == NE
}

// ---------------------------------------------------------------------------
// 3) scatter edges into CSR slots: csr[pos] = {col, weight_bits}
// ---------------------------------------------------------------------------
__global__ __launch_bounds__(256) void build_kernel(
    const int* __restrict__ erow, const int* __restrict__ ecol,
    const float* __restrict__ ew, int* __restrict__ cursor,
    int2* __restrict__ csr)
{
    int e = blockIdx.x * 256 + threadIdx.x;
    if (e >= NE) return;
    int r = erow[e];
    int pos = atomicAdd(&cursor[r], 1);
    int2 cw;
    cw.x = ecol[e];
    cw.y = __float_as_int(ew[e]);
    csr[pos] = cw;
}

// ---------------------------------------------------------------------------
// 4) gather: agg[i] = sum_{e in csr[i]} w_e * x[col_e]
//    32 lanes per node, float4 per lane (128 feats). No atomics.
// ---------------------------------------------------------------------------
__global__ __launch_bounds__(256) void gather_kernel(
    const float* __restrict__ x, const int* __restrict__ start,
    const int2* __restrict__ csr, float* __restrict__ agg)
{
    int t = threadIdx.x;
    int node = blockIdx.x * 8 + (t >> 5);
    int q = t & 31;
    if (node >= NN) return;
    int p = start[node];
    int pend = start[node + 1];
    const float4* x4 = (const float4*)x;
    float4 acc = make_float4(0.f, 0.f, 0.f, 0.f);
    // unroll by 2 for a bit of load ILP
    for (; p + 2 <= pend; p += 2) {
        int2 cw0 = csr[p];
        int2 cw1 = csr[p + 1];
        float w0 = __int_as_float(cw0.y);
        float w1 = __int_as_float(cw1.y);
        float4 v0 = x4[(size_t)cw0.x * 32 + q];
        float4 v1 = x4[(size_t)cw1.x * 32 + q];
        acc.x += w0 * v0.x; acc.y += w0 * v0.y;
        acc.z += w0 * v0.z; acc.w += w0 * v0.w;
        acc.x += w1 * v1.x; acc.y += w1 * v1.y;
        acc.z += w1 * v1.z; acc.w += w1 * v1.w;
    }
    if (p < pend) {
        int2 cw = csr[p];
        float w = __int_as_float(cw.y);
        float4 v = x4[(size_t)cw.x * 32 + q];
        acc.x += w * v.x; acc.y += w * v.y;
        acc.z += w * v.z; acc.w += w * v.w;
    }
    ((float4*)agg)[(size_t)node * 32 + q] = acc;
}

// ---------------------------------------------------------------------------
// 5) out = agg @ W + bias   (fp32 vector GEMM, LDS-tiled) — unchanged
// ---------------------------------------------------------------------------
#define BR 64
#define KT 64
#define XS (BR + 4)

__global__ __launch_bounds__(256) void gemm_bias_kernel(
    const float* __restrict__ agg,
    const float* __restrict__ W,
    const float* __restrict__ bias,
    float* __restrict__ out)
{
    __shared__ float Wt[KT * D];
    __shared__ float xT[KT * XS];

    int t = threadIdx.x;
    int row0 = blockIdx.x * BR;
    int tx = t & 31;
    int ty = t >> 5;
    int c0 = tx * 4;
    int r0 = ty * 8;

    float acc[8][4] = {};

    for (int kt = 0; kt < D; kt += KT) {
        {
            const float4* Wg = (const float4*)(W + (size_t)kt * D);
            float4* Ws = (float4*)Wt;
            #pragma unroll
            for (int i = 0; i < 8; ++i)
                Ws[t + i * 256] = Wg[t + i * 256];
        }
        #pragma unroll
        for (int i = 0; i < 4; ++i) {
            int v = t + i * 256;
            int r = v >> 4;
            int q = v & 15;
            int grow = row0 + r;
            float4 g = make_float4(0.f, 0.f, 0.f, 0.f);
            if (grow < NN)
                g = *(const float4*)(agg + (size_t)grow * D + kt + q * 4);
            xT[(q * 4 + 0) * XS + r] = g.x;
            xT[(q * 4 + 1) * XS + r] = g.y;
            xT[(q * 4 + 2) * XS + r] = g.z;
            xT[(q * 4 + 3) * XS + r] = g.w;
        }
        __syncthreads();

        #pragma unroll 4
        for (int k = 0; k < KT; ++k) {
            float4 wv = *(const float4*)(Wt + k * D + c0);
            float4 xa = *(const float4*)(xT + k * XS + r0);
            float4 xb = *(const float4*)(xT + k * XS + r0 + 4);
            float xs[8] = {xa.x, xa.y, xa.z, xa.w, xb.x, xb.y, xb.z, xb.w};
            float ws[4] = {wv.x, wv.y, wv.z, wv.w};
            #pragma unroll
            for (int i = 0; i < 8; ++i)
                #pragma unroll
                for (int j = 0; j < 4; ++j)
                    acc[i][j] += xs[i] * ws[j];
        }
        __syncthreads();
    }

    float4 bv = *(const float4*)(bias + c0);
    #pragma unroll
    for (int i = 0; i < 8; ++i) {
        int grow = row0 + r0 + i;
        if (grow < NN) {
            float4 o;
            o.x = acc[i][0] + bv.x;
            o.y = acc[i][1] + bv.y;
            o.z = acc[i][2] + bv.z;
            o.w = acc[i][3] + bv.w;
            *(float4*)(out + (size_t)grow * D + c0) = o;
        }
    }
}

extern "C" void kernel_launch(void* const* d_in, const int* in_sizes, int n_in,
                              void* d_out, int out_size, void* d_ws, size_t ws_size,
                              hipStream_t stream) {
    const float* x    = (const float*)d_in[0];
    const float* W    = (const float*)d_in[1];
    const float* bias = (const float*)d_in[2];
    const float* ew   = (const float*)d_in[3];
    const int*   erow = (const int*)d_in[4];
    const int*   ecol = (const int*)d_in[5];
    float* out = (float*)d_out;

    float* ws_f   = (float*)d_ws;
    float* agg    = ws_f + AGG_OFF;
    int*   counts = (int*)(ws_f + CNT_OFF);
    int*   start  = (int*)(ws_f + START_OFF);
    int*   cursor = (int*)(ws_f + CUR_OFF);
    int2*  csr    = (int2*)(ws_f + CSR_OFF);

    // zero the histogram counters only (cursor is written by scan_kernel)
    hipMemsetAsync(counts, 0, NPAD * sizeof(int), stream);

    hist_kernel<<<(NE + 255) / 256, 256, 0, stream>>>(erow, counts);
    scan_kernel<<<1, SCAN_T, 0, stream>>>(counts, start, cursor);
    build_kernel<<<(NE + 255) / 256, 256, 0, stream>>>(erow, ecol, ew, cursor, csr);
    gather_kernel<<<(NN + 7) / 8, 256, 0, stream>>>(x, start, csr, agg);
    gemm_bias_kernel<<<(NN + BR - 1) / BR, 256, 0, stream>>>(agg, W, bias, out);
}

// Round 3
// 261.509 us; speedup vs baseline: 5.5645x; 1.4414x over previous
//
#include <hip/hip_runtime.h>

#define NN 50000
#define NE 800000
#define D 128

#define NBLK 196            // ceil(NN/256)

// ws layout (in float/int units)
#define AGG_OFF   0                         // 50000*128 floats
#define NPAD      50016
#define CNT_OFF   (NN * D)
#define START_OFF (CNT_OFF + NPAD)
#define CUR_OFF   (START_OFF + NPAD)
#define BSUM_OFF  (CUR_OFF + NPAD)          // 256 ints
#define BOFF_OFF  (BSUM_OFF + 256)          // 256 ints
#define CSR_OFF   (BOFF_OFF + 256)          // 800000 int2

// ---------------------------------------------------------------------------
// 1) histogram of edge rows
// ---------------------------------------------------------------------------
__global__ __launch_bounds__(256) void hist_kernel(
    const int* __restrict__ erow, int* __restrict__ counts)
{
    int e = blockIdx.x * 256 + threadIdx.x;
    if (e < NE) atomicAdd(&counts[erow[e]], 1);
}

// ---------------------------------------------------------------------------
// 2a) per-block reduce of counts -> bsum[b]
// ---------------------------------------------------------------------------
__global__ __launch_bounds__(256) void reduce_kernel(
    const int* __restrict__ counts, int* __restrict__ bsum)
{
    __shared__ int s[256];
    int t = threadIdx.x;
    int idx = blockIdx.x * 256 + t;
    s[t] = (idx < NN) ? counts[idx] : 0;
    __syncthreads();
    #pragma unroll
    for (int off = 128; off > 0; off >>= 1) {
        if (t < off) s[t] += s[t + off];
        __syncthreads();
    }
    if (t == 0) bsum[blockIdx.x] = s[0];
}

// ---------------------------------------------------------------------------
// 2b) single-block scan of the 196 block sums -> boff[b] (exclusive)
// ---------------------------------------------------------------------------
__global__ __launch_bounds__(256) void scan_sums_kernel(
    const int* __restrict__ bsum, int* __restrict__ boff)
{
    __shared__ int s[256];
    int t = threadIdx.x;
    s[t] = (t < NBLK) ? bsum[t] : 0;
    __syncthreads();
    for (int off = 1; off < 256; off <<= 1) {
        int v = (t >= off) ? s[t - off] : 0;
        __syncthreads();
        s[t] += v;
        __syncthreads();
    }
    if (t < NBLK) boff[t] = (t == 0) ? 0 : s[t - 1];
}

// ---------------------------------------------------------------------------
// 2c) per-block local scan + offset -> start[], cursor[]; start[NN]=NE
// ---------------------------------------------------------------------------
__global__ __launch_bounds__(256) void apply_kernel(
    const int* __restrict__ counts, const int* __restrict__ boff,
    int* __restrict__ start, int* __restrict__ cursor)
{
    __shared__ int s[256];
    int t = threadIdx.x;
    int idx = blockIdx.x * 256 + t;
    int v = (idx < NN) ? counts[idx] : 0;
    s[t] = v;
    __syncthreads();
    for (int off = 1; off < 256; off <<= 1) {
        int u = (t >= off) ? s[t - off] : 0;
        __syncthreads();
        s[t] += u;
        __syncthreads();
    }
    int excl = boff[blockIdx.x] + s[t] - v;   // exclusive prefix
    if (idx < NN) {
        start[idx] = excl;
        cursor[idx] = excl;
    }
    if (blockIdx.x == 0 && t == 0) start[NN] = NE;
}

// ---------------------------------------------------------------------------
// 3) scatter edges into CSR slots: csr[pos] = {col, weight_bits}
// ---------------------------------------------------------------------------
__global__ __launch_bounds__(256) void build_kernel(
    const int* __restrict__ erow, const int* __restrict__ ecol,
    const float* __restrict__ ew, int* __restrict__ cursor,
    int2* __restrict__ csr)
{
    int e = blockIdx.x * 256 + threadIdx.x;
    if (e >= NE) return;
    int r = erow[e];
    int pos = atomicAdd(&cursor[r], 1);
    int2 cw;
    cw.x = ecol[e];
    cw.y = __float_as_int(ew[e]);
    csr[pos] = cw;
}

// ---------------------------------------------------------------------------
// 4) gather: agg[i] = sum_{e in csr[i]} w_e * x[col_e]; 32 lanes per node
// ---------------------------------------------------------------------------
__global__ __launch_bounds__(256) void gather_kernel(
    const float* __restrict__ x, const int* __restrict__ start,
    const int2* __restrict__ csr, float* __restrict__ agg)
{
    int t = threadIdx.x;
    int node = blockIdx.x * 8 + (t >> 5);
    int q = t & 31;
    if (node >= NN) return;
    int p = start[node];
    int pend = start[node + 1];
    const float4* x4 = (const float4*)x;
    float4 acc = make_float4(0.f, 0.f, 0.f, 0.f);
    // unroll by 4: 4 outstanding cache-line reads per lane
    for (; p + 4 <= pend; p += 4) {
        int2 cw0 = csr[p];
        int2 cw1 = csr[p + 1];
        int2 cw2 = csr[p + 2];
        int2 cw3 = csr[p + 3];
        float4 v0 = x4[(size_t)cw0.x * 32 + q];
        float4 v1 = x4[(size_t)cw1.x * 32 + q];
        float4 v2 = x4[(size_t)cw2.x * 32 + q];
        float4 v3 = x4[(size_t)cw3.x * 32 + q];
        float w0 = __int_as_float(cw0.y);
        float w1 = __int_as_float(cw1.y);
        float w2 = __int_as_float(cw2.y);
        float w3 = __int_as_float(cw3.y);
        acc.x += w0 * v0.x; acc.y += w0 * v0.y; acc.z += w0 * v0.z; acc.w += w0 * v0.w;
        acc.x += w1 * v1.x; acc.y += w1 * v1.y; acc.z += w1 * v1.z; acc.w += w1 * v1.w;
        acc.x += w2 * v2.x; acc.y += w2 * v2.y; acc.z += w2 * v2.z; acc.w += w2 * v2.w;
        acc.x += w3 * v3.x; acc.y += w3 * v3.y; acc.z += w3 * v3.z; acc.w += w3 * v3.w;
    }
    for (; p < pend; ++p) {
        int2 cw = csr[p];
        float w = __int_as_float(cw.y);
        float4 v = x4[(size_t)cw.x * 32 + q];
        acc.x += w * v.x; acc.y += w * v.y; acc.z += w * v.z; acc.w += w * v.w;
    }
    ((float4*)agg)[(size_t)node * 32 + q] = acc;
}

// ---------------------------------------------------------------------------
// 5) out = agg @ W + bias   (fp32 vector GEMM, LDS-tiled)
// ---------------------------------------------------------------------------
#define BR 64
#define KT 64
#define XS (BR + 4)

__global__ __launch_bounds__(256) void gemm_bias_kernel(
    const float* __restrict__ agg,
    const float* __restrict__ W,
    const float* __restrict__ bias,
    float* __restrict__ out)
{
    __shared__ float Wt[KT * D];
    __shared__ float xT[KT * XS];

    int t = threadIdx.x;
    int row0 = blockIdx.x * BR;
    int tx = t & 31;
    int ty = t >> 5;
    int c0 = tx * 4;
    int r0 = ty * 8;

    float acc[8][4] = {};

    for (int kt = 0; kt < D; kt += KT) {
        {
            const float4* Wg = (const float4*)(W + (size_t)kt * D);
            float4* Ws = (float4*)Wt;
            #pragma unroll
            for (int i = 0; i < 8; ++i)
                Ws[t + i * 256] = Wg[t + i * 256];
        }
        #pragma unroll
        for (int i = 0; i < 4; ++i) {
            int v = t + i * 256;
            int r = v >> 4;
            int q = v & 15;
            int grow = row0 + r;
            float4 g = make_float4(0.f, 0.f, 0.f, 0.f);
            if (grow < NN)
                g = *(const float4*)(agg + (size_t)grow * D + kt + q * 4);
            xT[(q * 4 + 0) * XS + r] = g.x;
            xT[(q * 4 + 1) * XS + r] = g.y;
            xT[(q * 4 + 2) * XS + r] = g.z;
            xT[(q * 4 + 3) * XS + r] = g.w;
        }
        __syncthreads();

        #pragma unroll 4
        for (int k = 0; k < KT; ++k) {
            float4 wv = *(const float4*)(Wt + k * D + c0);
            float4 xa = *(const float4*)(xT + k * XS + r0);
            float4 xb = *(const float4*)(xT + k * XS + r0 + 4);
            float xs[8] = {xa.x, xa.y, xa.z, xa.w, xb.x, xb.y, xb.z, xb.w};
            float ws[4] = {wv.x, wv.y, wv.z, wv.w};
            #pragma unroll
            for (int i = 0; i < 8; ++i)
                #pragma unroll
                for (int j = 0; j < 4; ++j)
                    acc[i][j] += xs[i] * ws[j];
        }
        __syncthreads();
    }

    float4 bv = *(const float4*)(bias + c0);
    #pragma unroll
    for (int i = 0; i < 8; ++i) {
        int grow = row0 + r0 + i;
        if (grow < NN) {
            float4 o;
            o.x = acc[i][0] + bv.x;
            o.y = acc[i][1] + bv.y;
            o.z = acc[i][2] + bv.z;
            o.w = acc[i][3] + bv.w;
            *(float4*)(out + (size_t)grow * D + c0) = o;
        }
    }
}

extern "C" void kernel_launch(void* const* d_in, const int* in_sizes, int n_in,
                              void* d_out, int out_size, void* d_ws, size_t ws_size,
                              hipStream_t stream) {
    const float* x    = (const float*)d_in[0];
    const float* W    = (const float*)d_in[1];
    const float* bias = (const float*)d_in[2];
    const float* ew   = (const float*)d_in[3];
    const int*   erow = (const int*)d_in[4];
    const int*   ecol = (const int*)d_in[5];
    float* out = (float*)d_out;

    float* ws_f   = (float*)d_ws;
    float* agg    = ws_f + AGG_OFF;
    int*   counts = (int*)(ws_f + CNT_OFF);
    int*   start  = (int*)(ws_f + START_OFF);
    int*   cursor = (int*)(ws_f + CUR_OFF);
    int*   bsum   = (int*)(ws_f + BSUM_OFF);
    int*   boff   = (int*)(ws_f + BOFF_OFF);
    int2*  csr    = (int2*)(ws_f + CSR_OFF);

    hipMemsetAsync(counts, 0, NPAD * sizeof(int), stream);

    hist_kernel<<<(NE + 255) / 256, 256, 0, stream>>>(erow, counts);
    reduce_kernel<<<NBLK, 256, 0, stream>>>(counts, bsum);
    scan_sums_kernel<<<1, 256, 0, stream>>>(bsum, boff);
    apply_kernel<<<NBLK, 256, 0, stream>>>(counts, boff, start, cursor);
    build_kernel<<<(NE + 255) / 256, 256, 0, stream>>>(erow, ecol, ew, cursor, csr);
    gather_kernel<<<(NN + 7) / 8, 256, 0, stream>>>(x, start, csr, agg);
    gemm_bias_kernel<<<(NN + BR - 1) / BR, 256, 0, stream>>>(agg, W, bias, out);
}

// Round 4
// 219.570 us; speedup vs baseline: 6.6274x; 1.1910x over previous
//
#include <hip/hip_runtime.h>
#include <hip/hip_bf16.h>

#define NN 50000
#define NE 800000
#define D 128

#define NBLK 196              // ceil(NN/256) for scan blocks

// grid split for fused cast/pack/hist kernel
#define CAST_BLKS 3125        // NN*D/8 threads / 256  (6.4M elems, 8 per thread)
#define PACK_BLKS 8           // 2048 threads: 8 tiles x 4 chunks x 64 lanes
#define HIST_BLKS 782         // NE/4 threads / 256

// ws layout in dword units
#define XH_OFF    0                       // x_h bf16: NN*D/2 dwords = 3,200,000
#define AGGH_OFF  3200000                 // agg_h bf16: 3,200,000
#define WF_OFF    6400000                 // W in B-frag order: 16384 bf16 = 8192
#define CNT_OFF   6408192                 // counts (reused as cursor): 50016
#define START_OFF 6458208                 // start: 50016 (needs NN+1)
#define BSUM_OFF  6508224                 // 256
#define BOFF_OFF  6508480                 // 256
#define CSR_OFF   6508736                 // NE int2 = 1,600,000 dwords

typedef short bf16x8 __attribute__((ext_vector_type(8)));
typedef float f32x4 __attribute__((ext_vector_type(4)));

__device__ inline unsigned short f2bf_u(float f) {
    __hip_bfloat16 h = __float2bfloat16(f);   // RNE
    return __builtin_bit_cast(unsigned short, h);
}
__device__ inline unsigned pack2(float a, float b) {
    return (unsigned)f2bf_u(a) | ((unsigned)f2bf_u(b) << 16);
}

// ---------------------------------------------------------------------------
// 1) fused: cast x->bf16 | pack W into MFMA-B-fragment order | histogram rows
// ---------------------------------------------------------------------------
__global__ __launch_bounds__(256) void cast_pack_hist_kernel(
    const float* __restrict__ x, const float* __restrict__ W,
    const int* __restrict__ erow,
    unsigned* __restrict__ x_h4,      // as dwords (2 bf16 each)
    unsigned short* __restrict__ Wf,  // 16384 bf16
    int* __restrict__ counts)
{
    int b = blockIdx.x;
    int t = threadIdx.x;
    if (b < CAST_BLKS) {
        // cast: 8 floats -> 8 bf16 (one uint4 store)
        int idx = b * 256 + t;                 // [0, 800000)
        const float4* x4 = (const float4*)x;
        float4 v0 = x4[idx * 2];
        float4 v1 = x4[idx * 2 + 1];
        uint4 o;
        o.x = pack2(v0.x, v0.y);
        o.y = pack2(v0.z, v0.w);
        o.z = pack2(v1.x, v1.y);
        o.w = pack2(v1.z, v1.w);
        ((uint4*)x_h4)[idx] = o;
    } else if (b < CAST_BLKS + PACK_BLKS) {
        // pack W[k][n] fp32 -> Wf in B-fragment order:
        // flat = ((nt*4 + c)*64 + lane); element j -> B[c*32 + (lane>>4)*8 + j][nt*16 + (lane&15)]
        int flat = (b - CAST_BLKS) * 256 + t;  // [0, 2048)
        int lane = flat & 63;
        int c    = (flat >> 6) & 3;
        int nt   = flat >> 8;
        int col  = nt * 16 + (lane & 15);
        int kb   = c * 32 + (lane >> 4) * 8;
        unsigned d[4];
        #pragma unroll
        for (int jj = 0; jj < 4; ++jj) {
            float a = W[(kb + 2 * jj) * D + col];
            float bb = W[(kb + 2 * jj + 1) * D + col];
            d[jj] = pack2(a, bb);
        }
        uint4 o; o.x = d[0]; o.y = d[1]; o.z = d[2]; o.w = d[3];
        ((uint4*)Wf)[flat] = o;
    } else {
        // histogram: 4 edges per thread
        int i4 = (b - CAST_BLKS - PACK_BLKS) * 256 + t;
        if (i4 < NE / 4) {
            int4 r = ((const int4*)erow)[i4];
            atomicAdd(&counts[r.x], 1);
            atomicAdd(&counts[r.y], 1);
            atomicAdd(&counts[r.z], 1);
            atomicAdd(&counts[r.w], 1);
        }
    }
}

// ---------------------------------------------------------------------------
// 2a) per-block reduce of counts -> bsum[b]
// ---------------------------------------------------------------------------
__global__ __launch_bounds__(256) void reduce_kernel(
    const int* __restrict__ counts, int* __restrict__ bsum)
{
    __shared__ int s[256];
    int t = threadIdx.x;
    int idx = blockIdx.x * 256 + t;
    s[t] = (idx < NN) ? counts[idx] : 0;
    __syncthreads();
    #pragma unroll
    for (int off = 128; off > 0; off >>= 1) {
        if (t < off) s[t] += s[t + off];
        __syncthreads();
    }
    if (t == 0) bsum[blockIdx.x] = s[0];
}

// ---------------------------------------------------------------------------
// 2b) single-block scan of block sums -> boff[b] (exclusive)
// ---------------------------------------------------------------------------
__global__ __launch_bounds__(256) void scan_sums_kernel(
    const int* __restrict__ bsum, int* __restrict__ boff)
{
    __shared__ int s[256];
    int t = threadIdx.x;
    s[t] = (t < NBLK) ? bsum[t] : 0;
    __syncthreads();
    for (int off = 1; off < 256; off <<= 1) {
        int v = (t >= off) ? s[t - off] : 0;
        __syncthreads();
        s[t] += v;
        __syncthreads();
    }
    if (t < NBLK) boff[t] = (t == 0) ? 0 : s[t - 1];
}

// ---------------------------------------------------------------------------
// 2c) local scan + offset -> start[]; cursor overlaid on counts[]
// ---------------------------------------------------------------------------
__global__ __launch_bounds__(256) void apply_kernel(
    int* __restrict__ counts, const int* __restrict__ boff,
    int* __restrict__ start)
{
    __shared__ int s[256];
    int t = threadIdx.x;
    int idx = blockIdx.x * 256 + t;
    int v = (idx < NN) ? counts[idx] : 0;
    s[t] = v;
    __syncthreads();
    for (int off = 1; off < 256; off <<= 1) {
        int u = (t >= off) ? s[t - off] : 0;
        __syncthreads();
        s[t] += u;
        __syncthreads();
    }
    int excl = boff[blockIdx.x] + s[t] - v;
    if (idx < NN) {
        start[idx] = excl;
        counts[idx] = excl;   // becomes the cursor for build
    }
    if (blockIdx.x == 0 && t == 0) start[NN] = NE;
}

// ---------------------------------------------------------------------------
// 3) scatter edges into CSR slots (4 edges/thread): csr[pos] = {col, w_bits}
// ---------------------------------------------------------------------------
__global__ __launch_bounds__(256) void build_kernel(
    const int* __restrict__ erow, const int* __restrict__ ecol,
    const float* __restrict__ ew, int* __restrict__ cursor,
    int2* __restrict__ csr)
{
    int i4 = blockIdx.x * 256 + threadIdx.x;
    if (i4 >= NE / 4) return;
    int4 r = ((const int4*)erow)[i4];
    int4 c = ((const int4*)ecol)[i4];
    float4 w = ((const float4*)ew)[i4];
    int p0 = atomicAdd(&cursor[r.x], 1);
    int p1 = atomicAdd(&cursor[r.y], 1);
    int p2 = atomicAdd(&cursor[r.z], 1);
    int p3 = atomicAdd(&cursor[r.w], 1);
    int2 e;
    e.x = c.x; e.y = __float_as_int(w.x); csr[p0] = e;
    e.x = c.y; e.y = __float_as_int(w.y); csr[p1] = e;
    e.x = c.z; e.y = __float_as_int(w.z); csr[p2] = e;
    e.x = c.w; e.y = __float_as_int(w.w); csr[p3] = e;
}

// ---------------------------------------------------------------------------
// 4) gather (bf16): agg_h[i] = bf16( sum_e w_e * x_h[col_e] )
//    16 lanes per node, 16 B (8 bf16) per lane, fp32 accumulation.
// ---------------------------------------------------------------------------
__device__ inline void acc8(float* acc, uint4 v, float w) {
    unsigned dw[4] = {v.x, v.y, v.z, v.w};
    #pragma unroll
    for (int i = 0; i < 4; ++i) {
        float lo = __int_as_float((int)(dw[i] << 16));
        float hi = __int_as_float((int)(dw[i] & 0xffff0000u));
        acc[2 * i]     += w * lo;
        acc[2 * i + 1] += w * hi;
    }
}

__global__ __launch_bounds__(256) void gather_kernel(
    const unsigned short* __restrict__ x_h, const int* __restrict__ start,
    const int2* __restrict__ csr, unsigned short* __restrict__ agg_h)
{
    int t = threadIdx.x;
    int node = blockIdx.x * 16 + (t >> 4);   // grid covers exactly NN
    int q = t & 15;
    int p = start[node];
    int pend = start[node + 1];
    const uint4* xv = (const uint4*)x_h;     // one row = 16 uint4
    float acc[8] = {};
    for (; p + 4 <= pend; p += 4) {
        int2 e0 = csr[p];
        int2 e1 = csr[p + 1];
        int2 e2 = csr[p + 2];
        int2 e3 = csr[p + 3];
        uint4 v0 = xv[(size_t)e0.x * 16 + q];
        uint4 v1 = xv[(size_t)e1.x * 16 + q];
        uint4 v2 = xv[(size_t)e2.x * 16 + q];
        uint4 v3 = xv[(size_t)e3.x * 16 + q];
        acc8(acc, v0, __int_as_float(e0.y));
        acc8(acc, v1, __int_as_float(e1.y));
        acc8(acc, v2, __int_as_float(e2.y));
        acc8(acc, v3, __int_as_float(e3.y));
    }
    for (; p < pend; ++p) {
        int2 e = csr[p];
        uint4 v = xv[(size_t)e.x * 16 + q];
        acc8(acc, v, __int_as_float(e.y));
    }
    uint4 o;
    o.x = pack2(acc[0], acc[1]);
    o.y = pack2(acc[2], acc[3]);
    o.z = pack2(acc[4], acc[5]);
    o.w = pack2(acc[6], acc[7]);
    ((uint4*)agg_h)[(size_t)node * 16 + q] = o;
}

// ---------------------------------------------------------------------------
// 5) out = agg_h @ W + bias  via mfma_f32_16x16x32_bf16, no LDS.
//    Block = 4 waves, 64 rows; wave = 16 rows x all 128 cols.
//    A frag: lane(m=lane&15, quad) holds A[m][c*32+quad*8 + j]  (16B load)
//    B frag: from Wf pre-swizzled: contiguous 16B per lane.
//    C/D:    col = lane&15, row = quad*4 + reg.
// ---------------------------------------------------------------------------
__global__ __launch_bounds__(256) void gemm_kernel(
    const unsigned short* __restrict__ agg_h,
    const unsigned short* __restrict__ Wf,
    const float* __restrict__ bias,
    float* __restrict__ out)
{
    int t = threadIdx.x;
    int wave = t >> 6;
    int lane = t & 63;
    int m = lane & 15;
    int quad = lane >> 4;
    int row0 = blockIdx.x * 64 + wave * 16;

    int arow = row0 + m;
    if (arow >= NN) arow = NN - 1;           // clamp; stores are guarded
    const bf16x8* ap = (const bf16x8*)(agg_h + (size_t)arow * D);
    bf16x8 a[4];
    #pragma unroll
    for (int c = 0; c < 4; ++c)
        a[c] = ap[c * 4 + quad];             // bf16 offset (c*32+quad*8)/8

    const bf16x8* bp = (const bf16x8*)Wf;
    #pragma unroll
    for (int nt = 0; nt < 8; ++nt) {
        f32x4 acc = {0.f, 0.f, 0.f, 0.f};
        #pragma unroll
        for (int c = 0; c < 4; ++c) {
            bf16x8 bfrag = bp[(nt * 4 + c) * 64 + lane];
            acc = __builtin_amdgcn_mfma_f32_16x16x32_bf16(a[c], bfrag, acc, 0, 0, 0);
        }
        float bcol = bias[nt * 16 + m];
        #pragma unroll
        for (int r = 0; r < 4; ++r) {
            int row = row0 + quad * 4 + r;
            if (row < NN)
                out[(size_t)row * D + nt * 16 + m] = acc[r] + bcol;
        }
    }
}

extern "C" void kernel_launch(void* const* d_in, const int* in_sizes, int n_in,
                              void* d_out, int out_size, void* d_ws, size_t ws_size,
                              hipStream_t stream) {
    const float* x    = (const float*)d_in[0];
    const float* W    = (const float*)d_in[1];
    const float* bias = (const float*)d_in[2];
    const float* ew   = (const float*)d_in[3];
    const int*   erow = (const int*)d_in[4];
    const int*   ecol = (const int*)d_in[5];
    float* out = (float*)d_out;

    unsigned* ws_u = (unsigned*)d_ws;
    unsigned*        x_h4   = ws_u + XH_OFF;
    unsigned short*  x_h    = (unsigned short*)x_h4;
    unsigned short*  agg_h  = (unsigned short*)(ws_u + AGGH_OFF);
    unsigned short*  Wf     = (unsigned short*)(ws_u + WF_OFF);
    int*             counts = (int*)(ws_u + CNT_OFF);   // doubles as cursor
    int*             start  = (int*)(ws_u + START_OFF);
    int*             bsum   = (int*)(ws_u + BSUM_OFF);
    int*             boff   = (int*)(ws_u + BOFF_OFF);
    int2*            csr    = (int2*)(ws_u + CSR_OFF);

    hipMemsetAsync(counts, 0, 50016 * sizeof(int), stream);

    cast_pack_hist_kernel<<<CAST_BLKS + PACK_BLKS + HIST_BLKS, 256, 0, stream>>>(
        x, W, erow, x_h4, Wf, counts);
    reduce_kernel<<<NBLK, 256, 0, stream>>>(counts, bsum);
    scan_sums_kernel<<<1, 256, 0, stream>>>(bsum, boff);
    apply_kernel<<<NBLK, 256, 0, stream>>>(counts, boff, start);
    build_kernel<<<(NE / 4 + 255) / 256, 256, 0, stream>>>(erow, ecol, ew, counts, csr);
    gather_kernel<<<NN / 16, 256, 0, stream>>>(x_h, start, csr, agg_h);
    gemm_kernel<<<(NN + 63) / 64, 256, 0, stream>>>(agg_h, Wf, bias, out);
}